// Round 5
// baseline (356.704 us; speedup 1.0000x reference)
//
#include <hip/hip_runtime.h>
#include <math.h>

#define NB   16
#define NN   16384
#define LDIM 512
#define DDIM 128
#define HIDD 128
#define NCLS 3
#define KCAP 256
#define CCAP 1024
#define EPSV 1e-8f
#define DELTA 0.02f

typedef float  f32x4  __attribute__((ext_vector_type(4)));
typedef int    i32x4  __attribute__((ext_vector_type(4)));
typedef unsigned u32x2 __attribute__((ext_vector_type(2)));
typedef __bf16 bf16x8 __attribute__((ext_vector_type(8)));
typedef unsigned long long u64;

__device__ __forceinline__ int get_k(const int* kp) {
    int k = kp[0];
    if (k < 1 || k > NN) {
        float f = __int_as_float(k);
        if (f >= 1.0f && f <= (float)NN) k = (int)f;
        else k = 70;
    }
    if (k > NN) k = NN;
    return k;
}

__device__ __forceinline__ unsigned okey(float f) {
    unsigned u = __float_as_uint(f);
    return (u & 0x80000000u) ? ~u : (u | 0x80000000u);
}
__device__ __forceinline__ float inv_okey(unsigned k) {
    unsigned u = (k & 0x80000000u) ? (k & 0x7FFFFFFFu) : ~k;
    return __uint_as_float(u);
}

// pack two fp32 -> two RNE bf16 in one u32 (a -> low, b -> high)  [r2/r3-proven]
__device__ __forceinline__ unsigned pk2bf(float a, float b) {
    unsigned ua = __float_as_uint(a); ua = (ua + 0x7FFFu + ((ua >> 16) & 1u)) >> 16;
    unsigned ub = __float_as_uint(b); ub = (ub + 0x7FFFu + ((ub >> 16) & 1u)) & 0xFFFF0000u;
    return (ua & 0xFFFFu) | ub;
}

__device__ __forceinline__ f32x4 mfma16(i32x4 a, i32x4 b, f32x4 c) {
    return __builtin_amdgcn_mfma_f32_16x16x32_bf16(
        __builtin_bit_cast(bf16x8, a), __builtin_bit_cast(bf16x8, b), c, 0, 0, 0);
}

__device__ __forceinline__ float sig_fast(float v)  { return 1.0f / (1.0f + __expf(-v)); }
__device__ __forceinline__ float tanh_fast(float v) { return 1.0f - 2.0f / (1.0f + __expf(2.0f * v)); }

// ---------------------------------------------------------------------------
// K0: swizzle Wv,Wu (fp32 [512][128]) into bf16 FRAGMENT-LANE order (r2-proven):
// short-idx = kt*8192 + g*4096 + nt*512 + lg*128 + lr*8 + j
//   (kt=k/32, lg=(k/8)%4, j=k%8, nt=n/16, lr=n%15) — a B-frag for (g,nt,kt)
//   is one contiguous 16B chunk per lane l = lg*16+lr.
// ---------------------------------------------------------------------------
__global__ void k0_prep(const float* __restrict__ Wv, const float* __restrict__ Wu,
                        unsigned short* __restrict__ Wp)
{
    int i = blockIdx.x * 256 + threadIdx.x;    // 0 .. 131071
    int g   = i >> 16;
    int rem = i & 65535;                       // kd*128 + n
    int kd  = rem >> 7;
    int n   = rem & 127;
    float w = g ? Wu[rem] : Wv[rem];
    unsigned u = __float_as_uint(w);
    u = (u + 0x7FFFu + ((u >> 16) & 1u)) >> 16;
    int kt = kd >> 5, lg = (kd >> 3) & 3, j = kd & 7, nt = n >> 4, lr = n & 15;
    Wp[kt * 8192 + g * 4096 + nt * 512 + lg * 128 + lr * 8 + j] = (unsigned short)u;
}

// ---------------------------------------------------------------------------
// K1: fused gated-attention logits, bf16 MFMA, weights WAVE-RESIDENT in VGPRs.
// Block 512 thr = 8 waves, BM=64 rows. Wave wid owns d-cols [wid*16,wid*16+16)
// for BOTH gates, all K (nt=wid covers ALL 8 n-tiles across 8 waves — this was
// the r4 bug: 4 waves only covered d<64). Wreg[2][16] i32x4 = 128 VGPR.
// LDS: x only, 2x4KB bf16 double-buffer (XOR chunk swizzle, r3-verified).
// Depth-2 global prefetch (two reg sets). One barrier per K-step (r3-proven).
// ---------------------------------------------------------------------------
__global__ __launch_bounds__(512, 1)
void k1_mfma(const float* __restrict__ x, const unsigned short* __restrict__ Wp,
             const float* __restrict__ bv, const float* __restrict__ bu,
             const float* __restrict__ Wa, const float* __restrict__ ba,
             float* __restrict__ logits)
{
    __shared__ __align__(16) char lds[8192];   // x dbuf: 2 x (64 rows x 32 bf16)

    const int t   = threadIdx.x;   // 0..511
    const int wid = t >> 6;        // 0..7
    const int l   = t & 63;
    const int lr  = l & 15;
    const int lg  = l >> 4;
    const int row0 = blockIdx.x * 64;

    // ---- wave-resident weights: frag (g, nt=wid, kt) at lane l ----
    i32x4 Wreg[2][16];
    {
        const unsigned short* wb = Wp + wid * 512 + l * 8;
#pragma unroll
        for (int kt = 0; kt < 16; ++kt) {
#pragma unroll
            for (int g = 0; g < 2; ++g)
                Wreg[g][kt] = *(const i32x4*)(wb + kt * 8192 + g * 4096);
        }
    }

    f32x4 acc[2][4];
#pragma unroll
    for (int g = 0; g < 2; ++g)
#pragma unroll
        for (int rt = 0; rt < 4; ++rt)
            acc[g][rt] = f32x4{0.f, 0.f, 0.f, 0.f};

    // staging: thread t stages row srow=(t>>3), 4-float group soct=(t&7)
    const int srow = t >> 3;
    const int soct = t & 7;
    const float* xsrc = x + (size_t)(row0 + srow) * LDIM + soct * 4;
    const int sswz = (srow >> 1) & 3;
    char* xw = lds + srow * 64 + (((soct >> 1) ^ sswz) * 16) + (soct & 1) * 8;

    // per-lane frag read offset: chunk = lg ^ ((row>>1)&3); rows rt*16+lr keep
    // (row>>1)&3 == (lr>>1)&3 for all rt (rt*8 ≡ 0 mod 4).
    const int fswz = (lg ^ ((lr >> 1) & 3)) * 16;

    // depth-2 prefetch: rA holds even tiles, rB odd tiles
    f32x4 rA = ((const f32x4*)xsrc)[0];
    f32x4 rB = ((const f32x4*)(xsrc + 32))[0];

#pragma unroll
    for (int kt = 0; kt < 16; ++kt) {
        const int p = kt & 1;
        // (1) pack + LDS write for tile kt
        f32x4 cur = (kt & 1) ? rB : rA;   // kt is compile-time (full unroll)
        u32x2 wv;
        wv.x = pk2bf(cur.x, cur.y);
        wv.y = pk2bf(cur.z, cur.w);
        *(u32x2*)(xw + p * 4096) = wv;
        // (2) issue tile kt+2 load into the slot just consumed
        if (kt < 14) {
            f32x4 nv = ((const f32x4*)(xsrc + (size_t)(kt + 2) * 32))[0];
            if (kt & 1) rB = nv; else rA = nv;
        }
        __syncthreads();
        // (3) A-frag reads + MFMA (B from registers)
        const char* Xb = lds + p * 4096;
#pragma unroll
        for (int rt = 0; rt < 4; ++rt) {
            i32x4 a = *(const i32x4*)(Xb + (rt * 16 + lr) * 64 + fswz);
            acc[0][rt] = mfma16(a, Wreg[0][kt], acc[0][rt]);
            acc[1][rt] = mfma16(a, Wreg[1][kt], acc[1][rt]);
        }
    }

    // epilogue: per-row partial over this wave's 16 d-cols, cross-wave add.
    const int d = wid * 16 + lr;
    const float bvd = bv[d], bud = bu[d], wad = Wa[d];
    const float ba0 = ba[0];
    float* sEp = (float*)lds;   // [8 waves][64 rows] floats = 2KB (disjoint from
                                // buf1, which slow waves may still be reading)
#pragma unroll
    for (int rt = 0; rt < 4; ++rt) {
#pragma unroll
        for (int r = 0; r < 4; ++r) {
            float vv = tanh_fast(acc[0][rt][r] + bvd);
            float uu = sig_fast (acc[1][rt][r] + bud);
            float s  = vv * uu * wad;
            s += __shfl_xor(s, 1); s += __shfl_xor(s, 2);
            s += __shfl_xor(s, 4); s += __shfl_xor(s, 8);
            if (lr == 0) sEp[wid * 64 + rt * 16 + lg * 4 + r] = s;
        }
    }
    __syncthreads();
    if (t < 64) {
        float s = ba0;
#pragma unroll
        for (int w2 = 0; w2 < 8; ++w2) s += sEp[w2 * 64 + t];
        logits[row0 + t] = s;
    }
}

// ---------------------------------------------------------------------------
// K3a: fused band-classify + softmax (verbatim r3, verified).
// ---------------------------------------------------------------------------
__global__ void k3a_band_softmax(float* __restrict__ A, const float* __restrict__ mask,
                                 const int* __restrict__ kp, int* __restrict__ idxWS,
                                 int* __restrict__ candIdx, int* __restrict__ counts)
{
    __shared__ float sredf[4];
    __shared__ int sredi[4];
    __shared__ int sIn, sCand;
    const int b = blockIdx.x;
    const int t = threadIdx.x;
    const int w = t >> 6;
    int k = get_k(kp); if (k > KCAP) k = KCAP;
    float* Ab = A + (size_t)b * NN;
    const float* mb = mask + (size_t)b * NN;

    float raw[64]; u64 mbits = 0ULL;
#pragma unroll
    for (int j = 0; j < 64; ++j) {
        int i = t + j * 256;
        raw[j] = Ab[i];
        if (mb[i] > 0.0f) mbits |= (1ULL << j);
    }
    unsigned kk[64];
#pragma unroll
    for (int j = 0; j < 64; ++j) {
        float v = ((mbits >> j) & 1) ? raw[j] : -3.0e38f;
        kk[j] = okey(v);
    }
    unsigned lo = 0u, hi = 0xFFFFFFFFu;
    while (lo < hi) {
        unsigned span = hi - lo;
        unsigned mid = lo + (span >> 1) + (span & 1u);
        int c = 0;
#pragma unroll
        for (int j = 0; j < 64; ++j) c += (kk[j] >= mid) ? 1 : 0;
#pragma unroll
        for (int m2 = 1; m2 < 64; m2 <<= 1) c += __shfl_xor(c, m2);
        __syncthreads();
        if ((t & 63) == 0) sredi[w] = c;
        __syncthreads();
        c = sredi[0] + sredi[1] + sredi[2] + sredi[3];
        if (c >= k) lo = mid; else hi = mid - 1;
    }
    const float tv = inv_okey(lo);

    if (t == 0) { sIn = 0; sCand = 0; }
    __syncthreads();
    const float hiB = tv + DELTA, loB = tv - DELTA;
#pragma unroll
    for (int j = 0; j < 64; ++j) {
        int i = t + j * 256;
        float v = ((mbits >> j) & 1) ? raw[j] : -3.0e38f;
        if (v > hiB)       { int p = atomicAdd(&sIn, 1);   if (p < KCAP) idxWS[b * KCAP + p] = i; }
        else if (v >= loB) { int p = atomicAdd(&sCand, 1); if (p < CCAP) candIdx[b * CCAP + p] = i; }
    }

    float mx = -INFINITY;
#pragma unroll
    for (int j = 0; j < 64; ++j) mx = fmaxf(mx, raw[j]);
#pragma unroll
    for (int m2 = 1; m2 < 64; m2 <<= 1) mx = fmaxf(mx, __shfl_xor(mx, m2));
    __syncthreads();
    if ((t & 63) == 0) sredf[w] = mx;
    __syncthreads();
    mx = fmaxf(fmaxf(sredf[0], sredf[1]), fmaxf(sredf[2], sredf[3]));

    float sAll = 0.f, sM = 0.f;
#pragma unroll
    for (int j = 0; j < 64; ++j) {
        float e = __expf(raw[j] - mx);
        sAll += e;
        if ((mbits >> j) & 1) sM += e;
    }
#pragma unroll
    for (int m2 = 1; m2 < 64; m2 <<= 1) sAll += __shfl_xor(sAll, m2);
    __syncthreads();
    if ((t & 63) == 0) sredf[w] = sAll;
    __syncthreads();
    sAll = sredf[0] + sredf[1] + sredf[2] + sredf[3];
#pragma unroll
    for (int m2 = 1; m2 < 64; m2 <<= 1) sM += __shfl_xor(sM, m2);
    __syncthreads();
    if ((t & 63) == 0) sredf[w] = sM;
    __syncthreads();
    sM = sredf[0] + sredf[1] + sredf[2] + sredf[3];

    const float inv = 1.0f / (sM + EPSV * sAll);
#pragma unroll
    for (int j = 0; j < 64; ++j) {
        int i = t + j * 256;
        float e = __expf(raw[j] - mx);
        Ab[i] = ((mbits >> j) & 1) ? e * inv : 0.0f;
    }
    if (t == 0) {
        int m1 = sIn;   if (m1 > k)    m1 = k;
        int cc = sCand; if (cc > CCAP) cc = CCAP;
        counts[b * 4]     = m1;
        counts[b * 4 + 1] = cc;
    }
}

// ---------------------------------------------------------------------------
// K3b: exact fp32 logits for band candidates (verbatim r3, verified).
// ---------------------------------------------------------------------------
__global__ void k3b_exact(const float* __restrict__ x,
                          const float* __restrict__ Wv, const float* __restrict__ bv,
                          const float* __restrict__ Wu, const float* __restrict__ bu,
                          const float* __restrict__ Wa, const float* __restrict__ ba,
                          const int* __restrict__ candIdx, const int* __restrict__ counts,
                          float* __restrict__ candVal)
{
    __shared__ float sx[LDIM];
    __shared__ float sr[2];
    const int b = blockIdx.x;
    const int t = threadIdx.x;   // 0..127
    const int cnt = counts[b * 4 + 1];
    for (int ci = blockIdx.y; ci < cnt; ci += gridDim.y) {
        const int row = candIdx[b * CCAP + ci];
        const float* xr = x + ((size_t)b * NN + (size_t)row) * LDIM;
        ((f32x4*)sx)[t] = ((const f32x4*)xr)[t];
        __syncthreads();
        float dv = bv[t], du = bu[t];
        for (int ll = 0; ll < LDIM; ++ll) {
            float xv = sx[ll];
            dv = fmaf(xv, Wv[ll * DDIM + t], dv);
            du = fmaf(xv, Wu[ll * DDIM + t], du);
        }
        float c = tanhf(dv) * (1.0f / (1.0f + expf(-du))) * Wa[t];
#pragma unroll
        for (int m2 = 1; m2 < 64; m2 <<= 1) c += __shfl_xor(c, m2);
        if ((t & 63) == 0) sr[t >> 6] = c;
        __syncthreads();
        if (t == 0) candVal[b * CCAP + ci] = sr[0] + sr[1] + ba[0];
        __syncthreads();
    }
}

// ---------------------------------------------------------------------------
// K34: select + rank-sort + gather + mean-pool + MLP + argmax (verbatim r3).
// ---------------------------------------------------------------------------
__global__ void k34_select_final(const float* __restrict__ x, const int* __restrict__ kp,
                                 const int* __restrict__ candIdx, const float* __restrict__ candVal,
                                 const int* __restrict__ counts, const int* __restrict__ idxWS,
                                 const float* __restrict__ W1, const float* __restrict__ b1,
                                 const float* __restrict__ W2, const float* __restrict__ b2,
                                 float* __restrict__ Yprob, float* __restrict__ Yhat)
{
    __shared__ u64 keys[CCAP];
    __shared__ int sIdx[KCAP];
    __shared__ int sFinal[KCAP];
    __shared__ int sPos;
    __shared__ float sPooled[LDIM];
    __shared__ float sH[HIDD];
    __shared__ float sY[4];
    const int b = blockIdx.x;
    const int t = threadIdx.x;
    int k = get_k(kp); if (k > KCAP) k = KCAP;
    const int m1  = counts[b * 4];
    const int cnt = counts[b * 4 + 1];
    int need = k - m1; if (need < 0) need = 0; if (need > cnt) need = cnt;

    for (int i = t; i < cnt; i += 256)
        keys[i] = (((u64)okey(candVal[b * CCAP + i])) << 14)
                | (u64)(16383 - candIdx[b * CCAP + i]);
    if (t < m1) sIdx[t] = idxWS[b * KCAP + t];
    if (t == 0) sPos = 0;
    if (t < KCAP) sFinal[t] = 0;
    __syncthreads();
    for (int i = t; i < cnt; i += 256) {
        u64 mk = keys[i];
        int rank = 0;
        for (int j = 0; j < cnt; ++j) rank += (keys[j] > mk) ? 1 : 0;
        if (rank < need) { int p = atomicAdd(&sPos, 1); sIdx[m1 + p] = candIdx[b * CCAP + i]; }
    }
    __syncthreads();
    int tot = m1 + need; if (tot > k) tot = k;
    if (t < tot) {
        int myv = sIdx[t];
        int rank = 0;
        for (int e = 0; e < tot; ++e) rank += (sIdx[e] < myv) ? 1 : 0;
        sFinal[rank] = myv;
    }
    __syncthreads();

    float a0 = 0.0f, a1 = 0.0f;
    for (int j = 0; j < k; ++j) {
        const float* xr = x + ((size_t)b * NN + (size_t)sFinal[j]) * LDIM;
        a0 += xr[t];
        a1 += xr[t + 256];
    }
    const float invk = 1.0f / (float)k;
    sPooled[t]       = a0 * invk;
    sPooled[t + 256] = a1 * invk;
    __syncthreads();

    if (t < HIDD) {
        float acc = b1[t];
        for (int ll = 0; ll < LDIM; ++ll) acc = fmaf(sPooled[ll], W1[ll * HIDD + t], acc);
        sH[t] = fmaxf(acc, 0.0f);
    }
    __syncthreads();
    if (t < NCLS) {
        float y = b2[t];
        for (int h = 0; h < HIDD; ++h) y = fmaf(sH[h], W2[h * NCLS + t], y);
        Yprob[b * NCLS + t] = y;
        sY[t] = y;
    }
    __syncthreads();
    if (t == 0) {
        int am = 0; float bst = sY[0];
        if (sY[1] > bst) { bst = sY[1]; am = 1; }
        if (sY[2] > bst) { bst = sY[2]; am = 2; }
        Yhat[b] = (float)am;
    }
}

// ---------------------------------------------------------------------------
extern "C" void kernel_launch(void* const* d_in, const int* in_sizes, int n_in,
                              void* d_out, int out_size, void* d_ws, size_t ws_size,
                              hipStream_t stream)
{
    const float* x    = (const float*)d_in[0];
    const float* mask = (const float*)d_in[1];
    const float* Wv   = (const float*)d_in[2];
    const float* bv   = (const float*)d_in[3];
    const float* Wu   = (const float*)d_in[4];
    const float* bu   = (const float*)d_in[5];
    const float* Wa   = (const float*)d_in[6];
    const float* ba   = (const float*)d_in[7];
    const float* W1   = (const float*)d_in[8];
    const float* b1   = (const float*)d_in[9];
    const float* W2   = (const float*)d_in[10];
    const float* b2   = (const float*)d_in[11];
    const int*   kp   = (const int*)d_in[12];

    float* out   = (float*)d_out;
    float* Yprob = out;        // [16,3] = 48
    float* Yhat  = out + 48;   // [16]
    float* A     = out + 64;   // [16,16384]  (logits first, softmax in-place)

    char* wsb = (char*)d_ws;
    unsigned short* Wp = (unsigned short*)wsb;        // 262144 B
    int*   idxWS   = (int*)  (wsb + 262144);          // 16 KB
    int*   candIdx = (int*)  (wsb + 278528);          // 64 KB
    float* candVal = (float*)(wsb + 344064);          // 64 KB
    int*   counts  = (int*)  (wsb + 409600);          // 256 B

    k0_prep  <<<512, 256, 0, stream>>>(Wv, Wu, Wp);
    k1_mfma  <<<4096, 512, 0, stream>>>(x, Wp, bv, bu, Wa, ba, A);
    k3a_band_softmax<<<NB, 256, 0, stream>>>(A, mask, kp, idxWS, candIdx, counts);
    k3b_exact<<<dim3(NB, 32), 128, 0, stream>>>(x, Wv, bv, Wu, bu, Wa, ba,
                                                candIdx, counts, candVal);
    k34_select_final<<<NB, 256, 0, stream>>>(x, kp, candIdx, candVal, counts, idxWS,
                                             W1, b1, W2, b2, Yprob, Yhat);
}

// Round 6
// 322.727 us; speedup vs baseline: 1.1053x; 1.1053x over previous
//
#include <hip/hip_runtime.h>
#include <math.h>

#define NB   16
#define NN   16384
#define LDIM 512
#define DDIM 128
#define HIDD 128
#define NCLS 3
#define KCAP 256
#define CCAP 1024
#define ROWB 8
#define EPSV 1e-8f
#define DELTA 0.02f

typedef float  f32x4  __attribute__((ext_vector_type(4)));
typedef int    i32x4  __attribute__((ext_vector_type(4)));
typedef __bf16 bf16x8 __attribute__((ext_vector_type(8)));
typedef unsigned long long u64;

__device__ __forceinline__ int get_k(const int* kp) {
    int k = kp[0];
    if (k < 1 || k > NN) {
        float f = __int_as_float(k);
        if (f >= 1.0f && f <= (float)NN) k = (int)f;
        else k = 70;
    }
    if (k > NN) k = NN;
    return k;
}

__device__ __forceinline__ unsigned okey(float f) {
    unsigned u = __float_as_uint(f);
    return (u & 0x80000000u) ? ~u : (u | 0x80000000u);
}
__device__ __forceinline__ float inv_okey(unsigned k) {
    unsigned u = (k & 0x80000000u) ? (k & 0x7FFFFFFFu) : ~k;
    return __uint_as_float(u);
}

// pack two fp32 -> two RNE bf16 in one u32 (a -> low, b -> high)  [r2/r3-proven]
__device__ __forceinline__ unsigned pk2bf(float a, float b) {
    unsigned ua = __float_as_uint(a); ua = (ua + 0x7FFFu + ((ua >> 16) & 1u)) >> 16;
    unsigned ub = __float_as_uint(b); ub = (ub + 0x7FFFu + ((ub >> 16) & 1u)) & 0xFFFF0000u;
    return (ua & 0xFFFFu) | ub;
}

__device__ __forceinline__ f32x4 mfma16(i32x4 a, i32x4 b, f32x4 c) {
    return __builtin_amdgcn_mfma_f32_16x16x32_bf16(
        __builtin_bit_cast(bf16x8, a), __builtin_bit_cast(bf16x8, b), c, 0, 0, 0);
}

__device__ __forceinline__ float sig_fast(float v)  { return 1.0f / (1.0f + __expf(-v)); }
__device__ __forceinline__ float tanh_fast(float v) { return 1.0f - 2.0f / (1.0f + __expf(2.0f * v)); }

// ---------------------------------------------------------------------------
// K0: swizzle Wv,Wu (fp32 [512][128]) into bf16 FRAGMENT-LANE order (r2-proven):
// short-idx = kt*8192 + g*4096 + nt*512 + lg*128 + lr*8 + j
//   (kt=k/32, lg=(k/8)%4, j=k%8, nt=n/16, lr=n%16)
// ---------------------------------------------------------------------------
__global__ void k0_prep(const float* __restrict__ Wv, const float* __restrict__ Wu,
                        unsigned short* __restrict__ Wp)
{
    int i = blockIdx.x * 256 + threadIdx.x;    // 0 .. 131071
    int g   = i >> 16;
    int rem = i & 65535;                       // kd*128 + n
    int kd  = rem >> 7;
    int n   = rem & 127;
    float w = g ? Wu[rem] : Wv[rem];
    unsigned u = __float_as_uint(w);
    u = (u + 0x7FFFu + ((u >> 16) & 1u)) >> 16;
    int kt = kd >> 5, lg = (kd >> 3) & 3, j = kd & 7, nt = n >> 4, lr = n & 15;
    Wp[kt * 8192 + g * 4096 + nt * 512 + lg * 128 + lr * 8 + j] = (unsigned short)u;
}

// ---------------------------------------------------------------------------
// K1: fused gated-attention logits via bf16 MFMA, LDS-staged (verbatim r3,
// the measured-best config: 256 thr = 4 waves, 2 blocks/CU, BM=128 rows;
// X dbuf 2x8KB (XOR chunk swizzle) + B dbuf 2x16KB; 1 barrier per K-step).
// ---------------------------------------------------------------------------
__global__ __launch_bounds__(256, 2)
void k1_mfma(const float* __restrict__ x, const unsigned short* __restrict__ Wp,
             const float* __restrict__ bv, const float* __restrict__ bu,
             const float* __restrict__ Wa, const float* __restrict__ ba,
             float* __restrict__ logits)
{
    __shared__ __align__(16) char lds[49152];  // X0 X1 (8KB ea) | B0 B1 (16KB ea)

    const int t   = threadIdx.x;
    const int wid = t >> 6;
    const int l   = t & 63;
    const int lr  = l & 15;
    const int lg  = l >> 4;
    const int row0  = blockIdx.x * 128;
    const int row0w = row0 + wid * 32;

    // staging roles: thread t stages x row (t>>1), half h=(t&1) (16 floats)
    const int srow = t >> 1;
    const int sh   = t & 1;
    const float* xsrc = x + (size_t)(row0 + srow) * LDIM + sh * 16;
    const int sswz = (srow >> 1) & 3;
    char* xw0 = lds + srow * 64 + (((sh * 2 + 0) ^ sswz) * 16);
    char* xw1 = lds + srow * 64 + (((sh * 2 + 1) ^ sswz) * 16);
    const unsigned short* bsrc = Wp + t * 8;   // + q*2048 shorts, + kt*8192 shorts
    char* bw = lds + 16384 + t * 16;           // + q*4096 bytes

    f32x4 acc[2][2][8];
#pragma unroll
    for (int g = 0; g < 2; ++g)
#pragma unroll
        for (int rt = 0; rt < 2; ++rt)
#pragma unroll
            for (int nt = 0; nt < 8; ++nt)
                acc[g][rt][nt] = f32x4{0.f, 0.f, 0.f, 0.f};

    // prologue: global loads for kt=0
    f32x4 xg[4]; i32x4 bg[4];
#pragma unroll
    for (int q = 0; q < 4; ++q) xg[q] = ((const f32x4*)xsrc)[q];
#pragma unroll
    for (int q = 0; q < 4; ++q) bg[q] = *(const i32x4*)(bsrc + q * 2048);

    // per-lane frag read offsets (constant)
    const int fswz = (lg ^ ((lr >> 1) & 3)) * 16;
    const int xr0  = (wid * 32 + lr) * 64 + fswz;
    const int xr1  = (wid * 32 + 16 + lr) * 64 + fswz;

#pragma unroll 2
    for (int kt = 0; kt < 16; ++kt) {
        const int p = kt & 1;
        // (1) pack + LDS writes for tile kt
        i32x4 wv0, wv1;
        wv0.x = pk2bf(xg[0].x, xg[0].y); wv0.y = pk2bf(xg[0].z, xg[0].w);
        wv0.z = pk2bf(xg[1].x, xg[1].y); wv0.w = pk2bf(xg[1].z, xg[1].w);
        wv1.x = pk2bf(xg[2].x, xg[2].y); wv1.y = pk2bf(xg[2].z, xg[2].w);
        wv1.z = pk2bf(xg[3].x, xg[3].y); wv1.w = pk2bf(xg[3].z, xg[3].w);
        *(i32x4*)(xw0 + p * 8192) = wv0;
        *(i32x4*)(xw1 + p * 8192) = wv1;
#pragma unroll
        for (int q = 0; q < 4; ++q) *(i32x4*)(bw + p * 16384 + q * 4096) = bg[q];
        // (2) issue next tile's global loads (fly across barrier + MFMA)
        if (kt < 15) {
            const float* xs = xsrc + (size_t)(kt + 1) * 32;
#pragma unroll
            for (int q = 0; q < 4; ++q) xg[q] = ((const f32x4*)xs)[q];
            const unsigned short* bs = bsrc + (size_t)(kt + 1) * 8192;
#pragma unroll
            for (int q = 0; q < 4; ++q) bg[q] = *(const i32x4*)(bs + q * 2048);
        }
        __syncthreads();
        // (3) frag reads + MFMA
        const char* Xb = lds + p * 8192;
        const char* Bb = lds + 16384 + p * 16384;
        i32x4 a0 = *(const i32x4*)(Xb + xr0);
        i32x4 a1 = *(const i32x4*)(Xb + xr1);
#pragma unroll
        for (int g = 0; g < 2; ++g) {
#pragma unroll
            for (int nt = 0; nt < 8; ++nt) {
                i32x4 bf = *(const i32x4*)(Bb + g * 8192 + nt * 1024 + l * 16);
                acc[g][0][nt] = mfma16(a0, bf, acc[g][0][nt]);
                acc[g][1][nt] = mfma16(a1, bf, acc[g][1][nt]);
            }
        }
    }

    // epilogue: tanh(V+bv)*sigmoid(U+bu)*Wa, reduce over 128 cols
    float bvc[8], buc[8], wac[8];
#pragma unroll
    for (int nt = 0; nt < 8; ++nt) {
        int col = nt * 16 + lr;
        bvc[nt] = bv[col]; buc[nt] = bu[col]; wac[nt] = Wa[col];
    }
    const float ba0 = ba[0];
#pragma unroll
    for (int rt = 0; rt < 2; ++rt) {
#pragma unroll
        for (int r = 0; r < 4; ++r) {
            float s = 0.f;
#pragma unroll
            for (int nt = 0; nt < 8; ++nt) {
                float vv = tanh_fast(acc[0][rt][nt][r] + bvc[nt]);
                float uu = sig_fast (acc[1][rt][nt][r] + buc[nt]);
                s = fmaf(vv * uu, wac[nt], s);
            }
            s += __shfl_xor(s, 1); s += __shfl_xor(s, 2);
            s += __shfl_xor(s, 4); s += __shfl_xor(s, 8);
            if (lr == 0)
                logits[row0w + rt * 16 + lg * 4 + r] = s + ba0;
        }
    }
}

// ---------------------------------------------------------------------------
// K3a: fused band-classify + softmax (verbatim r3, verified).
// ---------------------------------------------------------------------------
__global__ void k3a_band_softmax(float* __restrict__ A, const float* __restrict__ mask,
                                 const int* __restrict__ kp, int* __restrict__ idxWS,
                                 int* __restrict__ candIdx, int* __restrict__ counts)
{
    __shared__ float sredf[4];
    __shared__ int sredi[4];
    __shared__ int sIn, sCand;
    const int b = blockIdx.x;
    const int t = threadIdx.x;
    const int w = t >> 6;
    int k = get_k(kp); if (k > KCAP) k = KCAP;
    float* Ab = A + (size_t)b * NN;
    const float* mb = mask + (size_t)b * NN;

    float raw[64]; u64 mbits = 0ULL;
#pragma unroll
    for (int j = 0; j < 64; ++j) {
        int i = t + j * 256;
        raw[j] = Ab[i];
        if (mb[i] > 0.0f) mbits |= (1ULL << j);
    }
    unsigned kk[64];
#pragma unroll
    for (int j = 0; j < 64; ++j) {
        float v = ((mbits >> j) & 1) ? raw[j] : -3.0e38f;
        kk[j] = okey(v);
    }
    unsigned lo = 0u, hi = 0xFFFFFFFFu;
    while (lo < hi) {
        unsigned span = hi - lo;
        unsigned mid = lo + (span >> 1) + (span & 1u);
        int c = 0;
#pragma unroll
        for (int j = 0; j < 64; ++j) c += (kk[j] >= mid) ? 1 : 0;
#pragma unroll
        for (int m2 = 1; m2 < 64; m2 <<= 1) c += __shfl_xor(c, m2);
        __syncthreads();
        if ((t & 63) == 0) sredi[w] = c;
        __syncthreads();
        c = sredi[0] + sredi[1] + sredi[2] + sredi[3];
        if (c >= k) lo = mid; else hi = mid - 1;
    }
    const float tv = inv_okey(lo);

    if (t == 0) { sIn = 0; sCand = 0; }
    __syncthreads();
    const float hiB = tv + DELTA, loB = tv - DELTA;
#pragma unroll
    for (int j = 0; j < 64; ++j) {
        int i = t + j * 256;
        float v = ((mbits >> j) & 1) ? raw[j] : -3.0e38f;
        if (v > hiB)       { int p = atomicAdd(&sIn, 1);   if (p < KCAP) idxWS[b * KCAP + p] = i; }
        else if (v >= loB) { int p = atomicAdd(&sCand, 1); if (p < CCAP) candIdx[b * CCAP + p] = i; }
    }

    float mx = -INFINITY;
#pragma unroll
    for (int j = 0; j < 64; ++j) mx = fmaxf(mx, raw[j]);
#pragma unroll
    for (int m2 = 1; m2 < 64; m2 <<= 1) mx = fmaxf(mx, __shfl_xor(mx, m2));
    __syncthreads();
    if ((t & 63) == 0) sredf[w] = mx;
    __syncthreads();
    mx = fmaxf(fmaxf(sredf[0], sredf[1]), fmaxf(sredf[2], sredf[3]));

    float sAll = 0.f, sM = 0.f;
#pragma unroll
    for (int j = 0; j < 64; ++j) {
        float e = __expf(raw[j] - mx);
        sAll += e;
        if ((mbits >> j) & 1) sM += e;
    }
#pragma unroll
    for (int m2 = 1; m2 < 64; m2 <<= 1) sAll += __shfl_xor(sAll, m2);
    __syncthreads();
    if ((t & 63) == 0) sredf[w] = sAll;
    __syncthreads();
    sAll = sredf[0] + sredf[1] + sredf[2] + sredf[3];
#pragma unroll
    for (int m2 = 1; m2 < 64; m2 <<= 1) sM += __shfl_xor(sM, m2);
    __syncthreads();
    if ((t & 63) == 0) sredf[w] = sM;
    __syncthreads();
    sM = sredf[0] + sredf[1] + sredf[2] + sredf[3];

    const float inv = 1.0f / (sM + EPSV * sAll);
#pragma unroll
    for (int j = 0; j < 64; ++j) {
        int i = t + j * 256;
        float e = __expf(raw[j] - mx);
        Ab[i] = ((mbits >> j) & 1) ? e * inv : 0.0f;
    }
    if (t == 0) {
        int m1 = sIn;   if (m1 > k)    m1 = k;
        int cc = sCand; if (cc > CCAP) cc = CCAP;
        counts[b * 4]     = m1;
        counts[b * 4 + 1] = cc;
    }
}

// ---------------------------------------------------------------------------
// K3b: exact fp32 logits for band candidates — ROW-BATCHED (new this round).
// Stage ROWB=8 candidate rows in LDS, walk Wv/Wu ONCE per group (coalesced:
// thread t <-> d-column t). W L2 traffic drops 8x vs per-row walk.
// ---------------------------------------------------------------------------
__global__ void k3b_exact(const float* __restrict__ x,
                          const float* __restrict__ Wv, const float* __restrict__ bv,
                          const float* __restrict__ Wu, const float* __restrict__ bu,
                          const float* __restrict__ Wa, const float* __restrict__ ba,
                          const int* __restrict__ candIdx, const int* __restrict__ counts,
                          float* __restrict__ candVal)
{
    __shared__ __align__(16) float sx[ROWB][LDIM];   // 16 KB
    __shared__ float sred[2][ROWB];
    const int b = blockIdx.x;
    const int t = threadIdx.x;          // 0..127  (thread t owns d-column t)
    const int w = t >> 6;
    const int cnt = counts[b * 4 + 1];
    const float bvt = bv[t], but = bu[t], wat = Wa[t], ba0 = ba[0];

    for (int base = blockIdx.y * ROWB; base < cnt; base += gridDim.y * ROWB) {
        const int nr = min(ROWB, cnt - base);
        for (int r = 0; r < nr; ++r) {
            const int row = candIdx[b * CCAP + base + r];
            ((f32x4*)&sx[r][0])[t] =
                ((const f32x4*)(x + ((size_t)b * NN + (size_t)row) * LDIM))[t];
        }
        __syncthreads();

        float dv[ROWB], du[ROWB];
#pragma unroll
        for (int r = 0; r < ROWB; ++r) { dv[r] = bvt; du[r] = but; }
#pragma unroll 4
        for (int ll = 0; ll < LDIM; ++ll) {
            const float wvl = Wv[ll * DDIM + t];
            const float wul = Wu[ll * DDIM + t];
#pragma unroll
            for (int r = 0; r < ROWB; ++r) {
                const float xv = sx[r][ll];   // LDS broadcast (uniform addr)
                dv[r] = fmaf(xv, wvl, dv[r]);
                du[r] = fmaf(xv, wul, du[r]);
            }
        }
#pragma unroll
        for (int r = 0; r < ROWB; ++r) {
            float c = tanhf(dv[r]) * (1.0f / (1.0f + expf(-du[r]))) * wat;
            c += __shfl_xor(c, 1);  c += __shfl_xor(c, 2);
            c += __shfl_xor(c, 4);  c += __shfl_xor(c, 8);
            c += __shfl_xor(c, 16); c += __shfl_xor(c, 32);
            if ((t & 63) == 0) sred[w][r] = c;
        }
        __syncthreads();
        if (t < nr) candVal[b * CCAP + base + t] = sred[0][t] + sred[1][t] + ba0;
        __syncthreads();
    }
}

// ---------------------------------------------------------------------------
// K34: select + rank-sort + gather + mean-pool + MLP + argmax (verbatim r3).
// ---------------------------------------------------------------------------
__global__ void k34_select_final(const float* __restrict__ x, const int* __restrict__ kp,
                                 const int* __restrict__ candIdx, const float* __restrict__ candVal,
                                 const int* __restrict__ counts, const int* __restrict__ idxWS,
                                 const float* __restrict__ W1, const float* __restrict__ b1,
                                 const float* __restrict__ W2, const float* __restrict__ b2,
                                 float* __restrict__ Yprob, float* __restrict__ Yhat)
{
    __shared__ u64 keys[CCAP];
    __shared__ int sIdx[KCAP];
    __shared__ int sFinal[KCAP];
    __shared__ int sPos;
    __shared__ float sPooled[LDIM];
    __shared__ float sH[HIDD];
    __shared__ float sY[4];
    const int b = blockIdx.x;
    const int t = threadIdx.x;
    int k = get_k(kp); if (k > KCAP) k = KCAP;
    const int m1  = counts[b * 4];
    const int cnt = counts[b * 4 + 1];
    int need = k - m1; if (need < 0) need = 0; if (need > cnt) need = cnt;

    for (int i = t; i < cnt; i += 256)
        keys[i] = (((u64)okey(candVal[b * CCAP + i])) << 14)
                | (u64)(16383 - candIdx[b * CCAP + i]);
    if (t < m1) sIdx[t] = idxWS[b * KCAP + t];
    if (t == 0) sPos = 0;
    if (t < KCAP) sFinal[t] = 0;
    __syncthreads();
    for (int i = t; i < cnt; i += 256) {
        u64 mk = keys[i];
        int rank = 0;
        for (int j = 0; j < cnt; ++j) rank += (keys[j] > mk) ? 1 : 0;
        if (rank < need) { int p = atomicAdd(&sPos, 1); sIdx[m1 + p] = candIdx[b * CCAP + i]; }
    }
    __syncthreads();
    int tot = m1 + need; if (tot > k) tot = k;
    if (t < tot) {
        int myv = sIdx[t];
        int rank = 0;
        for (int e = 0; e < tot; ++e) rank += (sIdx[e] < myv) ? 1 : 0;
        sFinal[rank] = myv;
    }
    __syncthreads();

    float a0 = 0.0f, a1 = 0.0f;
    for (int j = 0; j < k; ++j) {
        const float* xr = x + ((size_t)b * NN + (size_t)sFinal[j]) * LDIM;
        a0 += xr[t];
        a1 += xr[t + 256];
    }
    const float invk = 1.0f / (float)k;
    sPooled[t]       = a0 * invk;
    sPooled[t + 256] = a1 * invk;
    __syncthreads();

    if (t < HIDD) {
        float acc = b1[t];
        for (int ll = 0; ll < LDIM; ++ll) acc = fmaf(sPooled[ll], W1[ll * HIDD + t], acc);
        sH[t] = fmaxf(acc, 0.0f);
    }
    __syncthreads();
    if (t < NCLS) {
        float y = b2[t];
        for (int h = 0; h < HIDD; ++h) y = fmaf(sH[h], W2[h * NCLS + t], y);
        Yprob[b * NCLS + t] = y;
        sY[t] = y;
    }
    __syncthreads();
    if (t == 0) {
        int am = 0; float bst = sY[0];
        if (sY[1] > bst) { bst = sY[1]; am = 1; }
        if (sY[2] > bst) { bst = sY[2]; am = 2; }
        Yhat[b] = (float)am;
    }
}

// ---------------------------------------------------------------------------
extern "C" void kernel_launch(void* const* d_in, const int* in_sizes, int n_in,
                              void* d_out, int out_size, void* d_ws, size_t ws_size,
                              hipStream_t stream)
{
    const float* x    = (const float*)d_in[0];
    const float* mask = (const float*)d_in[1];
    const float* Wv   = (const float*)d_in[2];
    const float* bv   = (const float*)d_in[3];
    const float* Wu   = (const float*)d_in[4];
    const float* bu   = (const float*)d_in[5];
    const float* Wa   = (const float*)d_in[6];
    const float* ba   = (const float*)d_in[7];
    const float* W1   = (const float*)d_in[8];
    const float* b1   = (const float*)d_in[9];
    const float* W2   = (const float*)d_in[10];
    const float* b2   = (const float*)d_in[11];
    const int*   kp   = (const int*)d_in[12];

    float* out   = (float*)d_out;
    float* Yprob = out;        // [16,3] = 48
    float* Yhat  = out + 48;   // [16]
    float* A     = out + 64;   // [16,16384]  (logits first, softmax in-place)

    char* wsb = (char*)d_ws;
    unsigned short* Wp = (unsigned short*)wsb;        // 262144 B
    int*   idxWS   = (int*)  (wsb + 262144);          // 16 KB
    int*   candIdx = (int*)  (wsb + 278528);          // 64 KB
    float* candVal = (float*)(wsb + 344064);          // 64 KB
    int*   counts  = (int*)  (wsb + 409600);          // 256 B

    k0_prep  <<<512, 256, 0, stream>>>(Wv, Wu, Wp);
    k1_mfma  <<<2048, 256, 0, stream>>>(x, Wp, bv, bu, Wa, ba, A);
    k3a_band_softmax<<<NB, 256, 0, stream>>>(A, mask, kp, idxWS, candIdx, counts);
    k3b_exact<<<dim3(NB, 32), 128, 0, stream>>>(x, Wv, bv, Wu, bu, Wa, ba,
                                                candIdx, counts, candVal);
    k34_select_final<<<NB, 256, 0, stream>>>(x, kp, candIdx, candVal, counts, idxWS,
                                             W1, b1, W2, b2, Yprob, Yhat);
}